// Round 6
// baseline (153.581 us; speedup 1.0000x reference)
//
#include <hip/hip_runtime.h>
#include <math.h>

// OLCNN: x(B,1,9,9) -> conv3x3(16ch) -> sigmoid (relu no-op) -> maxpool2x2
//        floor (7x7->3x3) -> conv2 (16*3x3->32) -> sigmoid -> fc 32->4.
// B = 131072 fp32. One thread = one sample; 512 blocks x 256 = 2 waves/SIMD
// (grid-pinned occupancy; VGPR budget 256).
//
// Round 6 — move the weight stream off the LDS pipe onto the scalar pipe:
//  * R5 post-mortem: 2520 ds_read_b64/thread x ~6cyc x 8 waves/CU ~= 121k cyc
//    of LDS-pipe time vs 163k total => LDS pipe ~74% busy = the bottleneck.
//    Broadcast reads still pay full issue cost per instruction.
//  * conv2 weights: prep-permuted [pi][oc][48] contiguous, read as PLAIN
//    float with uniform indices from __restrict__ const global -> compiler
//    s_load_dwordx16 on the SMEM pipe (R3 proved this pattern scalarizes;
//    R4 proved v2f casts break it). conv2 math scalar v_fmac with SGPR
//    weight operand: +4.6k VALU cyc/wave, -14k LDS cyc/wave.
//  * conv1 stays packed fp32 (v_pk_fma) with w1/b1/fc/b2 in a 1.5 KB LDS
//    block (~230 ds_read/thread, negligible).
//  * x: per-band align-4 dwordx4 loads, asm-pinned (R5-proven resident;
//    FETCH 1.5x ideal from band overlap, acceptable).

typedef float v2f __attribute__((ext_vector_type(2)));
typedef float f4  __attribute__((ext_vector_type(4)));
typedef f4 uf4 __attribute__((aligned(4)));   // align-4 dwordx4 (x rows 4B-aligned)

#define BLOCK 256
#define LOG2E 1.4426950408889634f

// ws layout (floats):
//   [0..4608)    w2 band-perm [pi][oc][48], *log2e ; j = o*3+pj
//   [4608..4928) small block staged to LDS:
#define OFF_SMALL 4608
#define S_W1P  0      // [8][9][2]  = 144  (w1 * log2e, ch-paired)
#define S_B1P  144    // [8][2]     = 16   (b1 * log2e, ch-paired)
#define S_FCWP 160    // [4][16][2] = 128  (fc_w ch-paired)
#define S_B2S  288    // 32                (b2 * log2e)
#define SMALL_FLOATS 320
#define WS_FLOATS (OFF_SMALL + SMALL_FLOATS)

__device__ __forceinline__ float sig2(float s) {
    // arg pre-scaled by log2e: sigmoid = 1/(1+2^-s)
    return __builtin_amdgcn_rcpf(1.0f + __builtin_amdgcn_exp2f(-s));
}

__global__ void prep_kernel(const float* __restrict__ w1,
                            const float* __restrict__ b1,
                            const float* __restrict__ w2,
                            const float* __restrict__ b2,
                            const float* __restrict__ fcw,
                            float* __restrict__ ws) {
    int i = blockIdx.x * blockDim.x + threadIdx.x;
    if (i < 4608) {
        // ws[pi][oc][j] = w2[oc][o*9 + pi*3 + pj] * log2e, o=j/3, pj=j%3
        int j = i % 48;
        int oc = (i / 48) % 32;
        int pi = i / 1536;
        int o = j / 3, pj = j % 3;
        ws[i] = w2[oc * 144 + o * 9 + pi * 3 + pj] * LOG2E;
    } else if (i < WS_FLOATS) {
        int r = i - OFF_SMALL;
        float v;
        if (r < S_B1P) {                         // w1 ch-paired: [op][k][h]
            int h = r & 1, k = (r >> 1) % 9, op = (r >> 1) / 9;
            v = w1[(2 * op + h) * 9 + k] * LOG2E;
        } else if (r < S_FCWP) {                 // b1 ch-paired: [op][h]
            int q = r - S_B1P;
            v = b1[2 * (q >> 1) + (q & 1)] * LOG2E;
        } else if (r < S_B2S) {                  // fcw ch-paired: [row][j][h]
            int q = r - S_FCWP;
            int h = q & 1, j = (q >> 1) % 16, rr = (q >> 1) / 16;
            v = fcw[rr * 32 + 2 * j + h];
        } else {                                 // b2 * log2e
            v = b2[r - S_B2S] * LOG2E;
        }
        ws[i] = v;
    }
}

__global__ __launch_bounds__(BLOCK, 2) void olcnn_kernel(
    const float* __restrict__ xg,   // (B,81)
    const float* __restrict__ ws,   // permuted weights
    const float* __restrict__ fcb,  // (4,)
    float* __restrict__ out)        // (B,4)
{
    __shared__ __align__(16) float lws[SMALL_FLOATS];
    const int tid = threadIdx.x;

    // stage small weight block global -> LDS (80 x float4)
    if (tid < SMALL_FLOATS / 4)
        ((f4*)lws)[tid] = ((const f4*)(ws + OFF_SMALL))[tid];
    __syncthreads();

    const v2f* w1p   = (const v2f*)(lws + S_W1P);
    const v2f* b1p   = (const v2f*)(lws + S_B1P);
    const v2f* fcwp  = (const v2f*)(lws + S_FCWP);
    const float* b2s = lws + S_B2S;

    const int t = blockIdx.x * BLOCK + tid;
    const float* xs = xg + (long long)t * 81;

    float acc2[32];
    #pragma unroll
    for (int oc = 0; oc < 32; ++oc) acc2[oc] = b2s[oc];

    #pragma unroll 1                   // rolled: body fits I$
    for (int pi = 0; pi < 3; ++pi) {
        // x rows 2pi..2pi+3, cols 0..7 (2 align-4 dwordx4 per row), pinned
        float xb[4][8];
        #pragma unroll
        for (int r = 0; r < 4; ++r) {
            const float* rp = xs + (2 * pi + r) * 9;
            f4 a = *(const uf4*)rp;
            f4 b = *(const uf4*)(rp + 4);
            xb[r][0] = a.x; xb[r][1] = a.y; xb[r][2] = a.z; xb[r][3] = a.w;
            xb[r][4] = b.x; xb[r][5] = b.y; xb[r][6] = b.z; xb[r][7] = b.w;
        }
        #pragma unroll
        for (int r = 0; r < 4; ++r)
            #pragma unroll
            for (int c = 0; c < 8; ++c)
                asm volatile("" : "+v"(xb[r][c]));   // pin: no sink/remat

        // conv1 + pool + sigmoid for this band -> pband[48], feature j=o*3+pj
        float pband[48];
        #pragma unroll
        for (int op = 0; op < 8; ++op) {            // channel pair (2op,2op+1)
            v2f wv[9];
            #pragma unroll
            for (int k = 0; k < 9; ++k) wv[k] = w1p[op * 9 + k];  // ds_read
            const v2f bb = b1p[op];
            #pragma unroll
            for (int pj = 0; pj < 3; ++pj) {
                v2f vmax;
                #pragma unroll
                for (int dh = 0; dh < 2; ++dh)
                    #pragma unroll
                    for (int dw = 0; dw < 2; ++dw) {
                        v2f s = bb;
                        #pragma unroll
                        for (int i = 0; i < 3; ++i)
                            #pragma unroll
                            for (int jj = 0; jj < 3; ++jj) {
                                float xv = xb[dh + i][2 * pj + dw + jj];
                                s = __builtin_elementwise_fma(
                                        (v2f){xv, xv}, wv[i * 3 + jj], s);
                            }
                        if (dh == 0 && dw == 0) vmax = s;
                        else vmax = __builtin_elementwise_max(vmax, s);
                    }
                pband[(2 * op) * 3 + pj]     = sig2(vmax.x);
                pband[(2 * op + 1) * 3 + pj] = sig2(vmax.y);
            }
        }

        // conv2 band: scalar v_fmac with UNIFORM (SGPR) weights from global.
        // wb rows are 48 contiguous floats -> s_load_dwordx16 bursts on the
        // SMEM pipe, zero LDS / VMEM cost.
        const float* wb = ws + pi * 1536;
        #pragma unroll
        for (int oc = 0; oc < 32; ++oc) {
            float a = acc2[oc];
            #pragma unroll
            for (int j = 0; j < 48; ++j)
                a = fmaf(wb[oc * 48 + j], pband[j], a);
            acc2[oc] = a;
        }
    }

    // h2 = sigmoid(acc2) packed; fc 32->4 packed (weights from LDS)
    v2f h2[16];
    #pragma unroll
    for (int oc = 0; oc < 32; ++oc) {
        float h = sig2(acc2[oc]);
        if (oc & 1) h2[oc >> 1].y = h; else h2[oc >> 1].x = h;
    }
    v2f a0 = h2[0] * fcwp[0],  a1 = h2[0] * fcwp[16],
        a2 = h2[0] * fcwp[32], a3 = h2[0] * fcwp[48];
    #pragma unroll
    for (int j = 1; j < 16; ++j) {
        a0 = __builtin_elementwise_fma(h2[j], fcwp[0 * 16 + j], a0);
        a1 = __builtin_elementwise_fma(h2[j], fcwp[1 * 16 + j], a1);
        a2 = __builtin_elementwise_fma(h2[j], fcwp[2 * 16 + j], a2);
        a3 = __builtin_elementwise_fma(h2[j], fcwp[3 * 16 + j], a3);
    }
    ((float4*)out)[t] = make_float4(fcb[0] + a0.x + a0.y,
                                    fcb[1] + a1.x + a1.y,
                                    fcb[2] + a2.x + a2.y,
                                    fcb[3] + a3.x + a3.y);
}

extern "C" void kernel_launch(void* const* d_in, const int* in_sizes, int n_in,
                              void* d_out, int out_size, void* d_ws, size_t ws_size,
                              hipStream_t stream) {
    const float* x   = (const float*)d_in[0];
    const float* w1  = (const float*)d_in[1];
    const float* b1  = (const float*)d_in[2];
    const float* w2  = (const float*)d_in[3];
    const float* b2  = (const float*)d_in[4];
    const float* fcw = (const float*)d_in[5];
    const float* fcb = (const float*)d_in[6];
    float* out = (float*)d_out;
    float* ws  = (float*)d_ws;        // needs WS_FLOATS floats (~19.3 KB)

    prep_kernel<<<dim3((WS_FLOATS + 255) / 256), dim3(256), 0, stream>>>(
        w1, b1, w2, b2, fcw, ws);

    const int nB = in_sizes[0] / 81;  // 131072, divisible by BLOCK
    olcnn_kernel<<<dim3(nB / BLOCK), dim3(BLOCK), 0, stream>>>(x, ws, fcb, out);
}

// Round 8
// 107.861 us; speedup vs baseline: 1.4239x; 1.4239x over previous
//
#include <hip/hip_runtime.h>
#include <hip/hip_bf16.h>
#include <math.h>

// OLCNN: x(B,1,9,9) -> conv3x3(16ch) -> sigmoid -> maxpool2x2 floor (7x7->3x3)
//        -> conv2 (144->32) -> sigmoid -> fc 32->4.  B = 131072 fp32.
// One thread = one sample; 512 blocks x 256 = 2 waves/SIMD (grid-pinned).
//
// Round 8 = Round 7 with the compile fix (pack bf16 pairs via __bf16
// ext-vector, which IS trivially copyable, instead of __hip_bfloat162).
//
// Design (R7): conv2 via MFMA — weights amortized in registers across
// samples. R5/R6 proved per-sample weight streams hit a pipe wall on every
// path (LDS-BW floor ~30us, SMEM latency-bound ~35us+stalls). MFMA holds
// w2 B-fragments in 12 VGPRs/band (one coalesced dwordx4/lane, prep-permuted
// into exact fragment order) -> weight traffic/sample ~ 0.
//  * conv1 stays R5-proven packed fp32 (v_pk_fma) with w1/b1 from LDS.
//  * per band: 48 pooled sigmoids -> pack bf16 -> wave-local LDS
//    (stride 26 dw; gcd(26,32)=2 -> 2-way = free) -> A-frags -> 6 MFMA
//    32x32x16_bf16. Wave-local => NO barriers.
//  * A/B k-layout consistency: both fragments built with the SAME assumed
//    (lane>>5,j)->k map, so any within-K permutation error cancels. C/D
//    layout is HW-verified (m74/m101): col=lane&31,
//    row=(reg&3)+8*(reg>>2)+4*(lane>>5).
//  * epilogue: bias+sigmoid on C-layout regs -> LDS transpose (stride 34 dw,
//    conflict-free) -> per-thread packed fc -> coalesced float4 store.

typedef float v2f __attribute__((ext_vector_type(2)));
typedef float f4  __attribute__((ext_vector_type(4)));
typedef f4 uf4 __attribute__((aligned(4)));   // align-4 dwordx4 (x rows 4B-aligned)
typedef __bf16 bf16x2 __attribute__((ext_vector_type(2)));
typedef __bf16 bf16x8 __attribute__((ext_vector_type(8)));
typedef float f32x16 __attribute__((ext_vector_type(16)));
typedef unsigned int u32;
typedef u32 u32x2 __attribute__((ext_vector_type(2)));
typedef u32 u32x4 __attribute__((ext_vector_type(4)));

#define BLOCK 256
#define LOG2E 1.4426950408889634f

// ws layout:
//   bytes  [0 .. 9216): w2 B-frags bf16 [pi][kb][lane][j]  (3*3*64*8 u16)
//   floats [2304 .. 2624): small block staged to LDS:
#define OFF_SMALL 2304
#define S_W1P  0      // [8][9][2]  w1 * log2e, ch-paired
#define S_B1P  144    // [8][2]     b1 * log2e, ch-paired
#define S_FCWP 160    // [4][16][2] fc_w ch-paired
#define S_B2S  288    // [32]       b2 * log2e
#define SMALL_FLOATS 320
#define PREP_ITEMS (4608 + SMALL_FLOATS)

__device__ __forceinline__ float sig2(float s) {
    // arg pre-scaled by log2e: sigmoid = 1/(1+2^-s)
    return __builtin_amdgcn_rcpf(1.0f + __builtin_amdgcn_exp2f(-s));
}

__global__ void prep_kernel(const float* __restrict__ w1,
                            const float* __restrict__ b1,
                            const float* __restrict__ w2,
                            const float* __restrict__ b2,
                            const float* __restrict__ fcw,
                            float* __restrict__ ws) {
    int i = blockIdx.x * blockDim.x + threadIdx.x;
    if (i < 4608) {
        // B-frag: value at (pi, kb, lane, j) = w2[oc = lane&31][d] * log2e,
        // band-feature k = kb*16 + (lane>>5)*8 + j, d = (k/3)*9 + pi*3 + k%3
        int j = i & 7, lane = (i >> 3) & 63, kb = (i >> 9) % 3, pi = i / 1536;
        int k = kb * 16 + (lane >> 5) * 8 + j;
        int o = k / 3, pj = k - 3 * o;
        float v = w2[(lane & 31) * 144 + o * 9 + pi * 3 + pj] * LOG2E;
        ((__bf16*)ws)[i] = (__bf16)v;            // RNE convert
    } else if (i < PREP_ITEMS) {
        int r = i - 4608;
        float v;
        if (r < S_B1P) {                         // w1 ch-paired: [op][k][h]
            int h = r & 1, k = (r >> 1) % 9, op = (r >> 1) / 9;
            v = w1[(2 * op + h) * 9 + k] * LOG2E;
        } else if (r < S_FCWP) {                 // b1 ch-paired: [op][h]
            int q = r - S_B1P;
            v = b1[2 * (q >> 1) + (q & 1)] * LOG2E;
        } else if (r < S_B2S) {                  // fcw ch-paired: [row][j][h]
            int q = r - S_FCWP;
            int h = q & 1, j = (q >> 1) % 16, rr = (q >> 1) / 16;
            v = fcw[rr * 32 + 2 * j + h];
        } else {                                 // b2 * log2e
            v = b2[r - S_B2S] * LOG2E;
        }
        ws[OFF_SMALL + r] = v;
    }
}

__global__ __launch_bounds__(BLOCK, 2) void olcnn_kernel(
    const float* __restrict__ xg,   // (B,81)
    const float* __restrict__ wsf,  // prep output
    const float* __restrict__ fcb,  // (4,)
    float* __restrict__ out)        // (B,4)
{
    // per-wave scratch: pband (64 x 26 dw) then reused for h2 transpose
    // (64 x 34 dw). 2176 dw = 8704 B per wave.
    __shared__ u32 lds_scr[4 * 2176];
    __shared__ __align__(16) float lws[SMALL_FLOATS];

    const int tid  = threadIdx.x;
    const int lane = tid & 63;
    const int wid  = tid >> 6;
    u32* scr = lds_scr + wid * 2176;

    if (tid < SMALL_FLOATS / 4)
        ((f4*)lws)[tid] = ((const f4*)(wsf + OFF_SMALL))[tid];
    __syncthreads();

    const v2f* w1p  = (const v2f*)(lws + S_W1P);
    const v2f* b1p  = (const v2f*)(lws + S_B1P);
    const v2f* fcwp = (const v2f*)(lws + S_FCWP);

    const int t = blockIdx.x * BLOCK + tid;
    const float* xs = xg + (long long)t * 81;

    const u32x4* bfrag_g = (const u32x4*)wsf;   // [pi*3+kb][lane] x 16B

    f32x16 acc0{};                  // M-tile 0: samples 0..31 (wave-local)
    f32x16 acc1{};                  // M-tile 1: samples 32..63

    const int m0  = lane & 31;
    const int kha = (lane >> 5) * 4;            // A-frag dword sub-offset

    #pragma unroll 1                // rolled: body fits I$
    for (int pi = 0; pi < 3; ++pi) {
        // ---- x band rows 2pi..2pi+3, cols 0..7, asm-pinned (R5-proven) ----
        float xb[4][8];
        #pragma unroll
        for (int r = 0; r < 4; ++r) {
            const float* rp = xs + (2 * pi + r) * 9;
            f4 a = *(const uf4*)rp;
            f4 b = *(const uf4*)(rp + 4);
            xb[r][0] = a.x; xb[r][1] = a.y; xb[r][2] = a.z; xb[r][3] = a.w;
            xb[r][4] = b.x; xb[r][5] = b.y; xb[r][6] = b.z; xb[r][7] = b.w;
        }
        #pragma unroll
        for (int r = 0; r < 4; ++r)
            #pragma unroll
            for (int c = 0; c < 8; ++c)
                asm volatile("" : "+v"(xb[r][c]));

        // ---- conv1 + pool + sigmoid: 48 band features f = ch*3 + pj ----
        float p48[48];
        #pragma unroll
        for (int op = 0; op < 8; ++op) {        // channel pair (2op, 2op+1)
            v2f wv[9];
            #pragma unroll
            for (int k = 0; k < 9; ++k) wv[k] = w1p[op * 9 + k];
            const v2f bb = b1p[op];
            #pragma unroll
            for (int pj = 0; pj < 3; ++pj) {
                v2f vmax;
                #pragma unroll
                for (int dh = 0; dh < 2; ++dh)
                    #pragma unroll
                    for (int dw = 0; dw < 2; ++dw) {
                        v2f s = bb;
                        #pragma unroll
                        for (int i = 0; i < 3; ++i)
                            #pragma unroll
                            for (int jj = 0; jj < 3; ++jj) {
                                float xv = xb[dh + i][2 * pj + dw + jj];
                                s = __builtin_elementwise_fma(
                                        (v2f){xv, xv}, wv[i * 3 + jj], s);
                            }
                        if (dh == 0 && dw == 0) vmax = s;
                        else vmax = __builtin_elementwise_max(vmax, s);
                    }
                p48[(2 * op) * 3 + pj]     = sig2(vmax.x);
                p48[(2 * op + 1) * 3 + pj] = sig2(vmax.y);
            }
        }

        // ---- pack bf16 pairs, write own row (stride 26 dw; 2-way = free) --
        #pragma unroll
        for (int q = 0; q < 24; ++q) {
            bf16x2 hp;
            hp.x = (__bf16)p48[2 * q];
            hp.y = (__bf16)p48[2 * q + 1];
            scr[lane * 26 + q] = __builtin_bit_cast(u32, hp);
        }
        // (wave-local: compiler inserts lgkmcnt ordering, no barrier needed)

        // ---- 3 k-blocks of MFMA ----
        #pragma unroll
        for (int kb = 0; kb < 3; ++kb) {
            u32x4 bw = bfrag_g[(pi * 3 + kb) * 64 + lane];   // B-frag, cached
            bf16x8 bf = __builtin_bit_cast(bf16x8, bw);

            const int off = kb * 8 + kha;        // dword offset in sample row
            u32x2 a0l = *(const u32x2*)(scr + m0 * 26 + off);
            u32x2 a0h = *(const u32x2*)(scr + m0 * 26 + off + 2);
            u32x2 a1l = *(const u32x2*)(scr + (m0 + 32) * 26 + off);
            u32x2 a1h = *(const u32x2*)(scr + (m0 + 32) * 26 + off + 2);
            u32x4 aw0; aw0.x = a0l.x; aw0.y = a0l.y; aw0.z = a0h.x; aw0.w = a0h.y;
            u32x4 aw1; aw1.x = a1l.x; aw1.y = a1l.y; aw1.z = a1h.x; aw1.w = a1h.y;

            acc0 = __builtin_amdgcn_mfma_f32_32x32x16_bf16(
                       __builtin_bit_cast(bf16x8, aw0), bf, acc0, 0, 0, 0);
            acc1 = __builtin_amdgcn_mfma_f32_32x32x16_bf16(
                       __builtin_bit_cast(bf16x8, aw1), bf, acc1, 0, 0, 0);
        }
    }

    // ---- bias + sigmoid on C-layout regs, transpose via LDS ----
    // C/D: col(oc) = lane&31, row = (reg&3) + 8*(reg>>2) + 4*(lane>>5)
    const float b2v = lws[S_B2S + (lane & 31)];
    #pragma unroll
    for (int r = 0; r < 16; ++r) {
        const int srow = (r & 3) + 8 * (r >> 2) + 4 * (lane >> 5);
        scr[srow * 34 + (lane & 31)] =
            __builtin_bit_cast(u32, sig2(acc0[r] + b2v));
        scr[(srow + 32) * 34 + (lane & 31)] =
            __builtin_bit_cast(u32, sig2(acc1[r] + b2v));
    }

    // ---- per-thread fc 32->4 (packed), coalesced float4 store ----
    v2f h2[16];
    #pragma unroll
    for (int j = 0; j < 16; ++j)
        h2[j] = *(const v2f*)((const float*)scr + lane * 34 + 2 * j);

    v2f a0 = h2[0] * fcwp[0],  a1 = h2[0] * fcwp[16],
        a2 = h2[0] * fcwp[32], a3 = h2[0] * fcwp[48];
    #pragma unroll
    for (int j = 1; j < 16; ++j) {
        a0 = __builtin_elementwise_fma(h2[j], fcwp[0 * 16 + j], a0);
        a1 = __builtin_elementwise_fma(h2[j], fcwp[1 * 16 + j], a1);
        a2 = __builtin_elementwise_fma(h2[j], fcwp[2 * 16 + j], a2);
        a3 = __builtin_elementwise_fma(h2[j], fcwp[3 * 16 + j], a3);
    }
    ((float4*)out)[t] = make_float4(fcb[0] + a0.x + a0.y,
                                    fcb[1] + a1.x + a1.y,
                                    fcb[2] + a2.x + a2.y,
                                    fcb[3] + a3.x + a3.y);
}

extern "C" void kernel_launch(void* const* d_in, const int* in_sizes, int n_in,
                              void* d_out, int out_size, void* d_ws, size_t ws_size,
                              hipStream_t stream) {
    const float* x   = (const float*)d_in[0];
    const float* w1  = (const float*)d_in[1];
    const float* b1  = (const float*)d_in[2];
    const float* w2  = (const float*)d_in[3];
    const float* b2  = (const float*)d_in[4];
    const float* fcw = (const float*)d_in[5];
    const float* fcb = (const float*)d_in[6];
    float* out = (float*)d_out;
    float* ws  = (float*)d_ws;        // needs 9216 B frags + 1280 B = ~10.5 KB

    prep_kernel<<<dim3((PREP_ITEMS + 255) / 256), dim3(256), 0, stream>>>(
        w1, b1, w2, b2, fcw, ws);

    const int nB = in_sizes[0] / 81;  // 131072, divisible by BLOCK
    olcnn_kernel<<<dim3(nB / BLOCK), dim3(BLOCK), 0, stream>>>(x, ws, fcb, out);
}